// Round 4
// baseline (1106.708 us; speedup 1.0000x reference)
//
#include <hip/hip_runtime.h>

#define N_NODES 100000
#define G_NODES 50000
#define N_EDGES 800000
#define H 64
#define F_IN 32
#define MAX_DEG 20
#define NUM_GRAPHS 128
#define LN_EPS 1e-5f
#define POOL_BLOCKS 64

// ---------------- embedding: h = x @ emb_w + emb_b (wave-per-node, lane=c) ----
__global__ __launch_bounds__(256) void emb_kernel(
    const float* __restrict__ x, const float* __restrict__ w,
    const float* __restrict__ b, float* __restrict__ h, float* __restrict__ h0) {
  int node = blockIdx.x * 4 + (threadIdx.x >> 6);
  int c = threadIdx.x & 63;
  if (node >= N_NODES) return;
  float xv = (c < F_IN) ? x[node * F_IN + c] : 0.0f;
  float acc = b[c];
#pragma unroll
  for (int f = 0; f < F_IN; ++f) {
    float xf = __shfl(xv, f, 64);
    acc = fmaf(xf, w[f * H + c], acc);
  }
  int idx = node * H + c;
  h[idx] = acc;
  h0[idx] = acc;
}

// ---------------- CSR build ----------------
__global__ __launch_bounds__(256) void count_kernel(
    const int* __restrict__ e0, const int* __restrict__ e1,
    const int* __restrict__ e2, const int* __restrict__ e3,
    int* __restrict__ deg4) {
  int e = blockIdx.x * 256 + threadIdx.x;
  if (e >= N_EDGES) return;
  int j = blockIdx.y;
  const int* ei = (j == 0) ? e0 : (j == 1) ? e1 : (j == 2) ? e2 : e3;
  int dst = ei[N_EDGES + e];
  atomicAdd(&deg4[j * N_NODES + dst], 1);
}

// hierarchical exclusive scan of deg4 (M = 4*N). Each set sums to exactly
// N_EDGES, so concatenated offsets give global slot positions directly.
__global__ __launch_bounds__(256) void scan1(
    const int* __restrict__ in, int* __restrict__ S, int* __restrict__ bsum, int M) {
  int t = threadIdx.x;
  int base = blockIdx.x * 1024 + t * 4;
  int v0 = 0, v1 = 0, v2 = 0, v3 = 0;
  if (base + 3 < M) {
    int4 q = *(const int4*)(in + base);
    v0 = q.x; v1 = q.y; v2 = q.z; v3 = q.w;
  } else {
    if (base     < M) v0 = in[base];
    if (base + 1 < M) v1 = in[base + 1];
    if (base + 2 < M) v2 = in[base + 2];
    if (base + 3 < M) v3 = in[base + 3];
  }
  int s = v0 + v1 + v2 + v3;
  int incl = s;
#pragma unroll
  for (int off = 1; off < 64; off <<= 1) {
    int y = __shfl_up(incl, off, 64);
    if ((t & 63) >= off) incl += y;
  }
  __shared__ int wtot[4];
  if ((t & 63) == 63) wtot[t >> 6] = incl;
  __syncthreads();
  int wbase = 0;
  for (int w = 0; w < (t >> 6); ++w) wbase += wtot[w];
  int ex = wbase + incl - s;
  if (base < M) {
    int eo0 = ex, eo1 = ex + v0, eo2 = ex + v0 + v1, eo3 = ex + v0 + v1 + v2;
    if (base + 3 < M) {
      *(int4*)(S + base) = make_int4(eo0, eo1, eo2, eo3);
    } else {
      S[base] = eo0;
      if (base + 1 < M) S[base + 1] = eo1;
      if (base + 2 < M) S[base + 2] = eo2;
    }
  }
  if (t == 255) bsum[blockIdx.x] = wbase + incl;  // block total
}

__global__ __launch_bounds__(512) void scan2(int* __restrict__ bsum, int nb) {
  int t = threadIdx.x;
  int v = (t < nb) ? bsum[t] : 0;
  int incl = v;
#pragma unroll
  for (int off = 1; off < 64; off <<= 1) {
    int y = __shfl_up(incl, off, 64);
    if ((t & 63) >= off) incl += y;
  }
  __shared__ int wtot[8];
  if ((t & 63) == 63) wtot[t >> 6] = incl;
  __syncthreads();
  int wbase = 0;
  for (int w = 0; w < (t >> 6); ++w) wbase += wtot[w];
  if (t < nb) bsum[t] = wbase + incl - v;  // in-place exclusive
}

__global__ __launch_bounds__(256) void scan3(
    int* __restrict__ S, const int* __restrict__ bsum, int* __restrict__ cursor, int M) {
  int i = blockIdx.x * 256 + threadIdx.x;
  if (i >= M) return;
  int v = S[i] + bsum[i >> 10];
  S[i] = v;
  cursor[i] = v;
}

// slots written via atomicExch: atomics write through 4B payloads (R1 counter
// evidence: WRITE_SIZE ~= 4B/atomic), avoiding the 64B dirty-line eviction
// amplification a plain scattered store incurs (R3: 221 MB for 12.8 MB data).
__global__ __launch_bounds__(256) void fill_kernel(
    const int* __restrict__ e0, const int* __restrict__ e1,
    const int* __restrict__ e2, const int* __restrict__ e3,
    int* __restrict__ cursor, int* __restrict__ slots) {
  int e = blockIdx.x * 256 + threadIdx.x;
  if (e >= N_EDGES) return;
  int j = blockIdx.y;
  const int* ei = (j == 0) ? e0 : (j == 1) ? e1 : (j == 2) ? e2 : e3;
  int src = ei[e];
  int dst = ei[N_EDGES + e];
  int pos = atomicAdd(&cursor[j * N_NODES + dst], 1);
  atomicExch(&slots[pos], src);
}

// ---------------- degree-bucket lists (21 buckets per edge set) -------------
__global__ __launch_bounds__(256) void bucket_count(
    const int* __restrict__ deg4, int* __restrict__ bcnt) {
  __shared__ int hist[21];
  int t = threadIdx.x;
  if (t < 21) hist[t] = 0;
  __syncthreads();
  int node = blockIdx.x * 256 + t;
  int j = blockIdx.y;
  if (node < N_NODES) {
    int d = deg4[j * N_NODES + node];
    int b = d < MAX_DEG ? d : MAX_DEG;
    atomicAdd(&hist[b], 1);
  }
  __syncthreads();
  if (t < 21 && hist[t]) atomicAdd(&bcnt[j * 21 + t], hist[t]);
}

__global__ __launch_bounds__(128) void bucket_scan(
    const int* __restrict__ bcnt, int* __restrict__ boff, int* __restrict__ bcur) {
  int t = threadIdx.x;
  int v = (t < 84) ? bcnt[t] : 0;
  int incl = v;
#pragma unroll
  for (int off = 1; off < 64; off <<= 1) {
    int y = __shfl_up(incl, off, 64);
    if ((t & 63) >= off) incl += y;
  }
  __shared__ int wt[2];
  if ((t & 63) == 63) wt[t >> 6] = incl;
  __syncthreads();
  int wbase = (t >> 6) ? wt[0] : 0;
  if (t < 84) {
    int ex = wbase + incl - v;
    boff[t] = ex;
    bcur[t] = ex;
  }
}

__global__ __launch_bounds__(256) void bucket_fill(
    const int* __restrict__ deg4, int* __restrict__ bcur, int* __restrict__ blist) {
  __shared__ int hist[21];
  __shared__ int base[21];
  int t = threadIdx.x;
  if (t < 21) hist[t] = 0;
  __syncthreads();
  int node = blockIdx.x * 256 + t;
  int j = blockIdx.y;
  int b = 0, lpos = 0;
  bool valid = (node < N_NODES);
  if (valid) {
    int d = deg4[j * N_NODES + node];
    b = d < MAX_DEG ? d : MAX_DEG;
    lpos = atomicAdd(&hist[b], 1);
  }
  __syncthreads();
  if (t < 21 && hist[t]) base[t] = atomicAdd(&bcur[j * 21 + t], hist[t]);
  __syncthreads();
  if (valid) blist[base[b] + lpos] = node;
}

// ---------------- gather: hsum[i] = sum_{j->i} h[j] (CSR, no atomics) -------
// 4-way unrolled: 4 independent 256B gathers in flight per wave.
__global__ __launch_bounds__(256) void gather_kernel(
    const int* __restrict__ S, const int* __restrict__ deg,
    const int* __restrict__ slots, const float* __restrict__ h,
    float* __restrict__ hsum) {
  int node = blockIdx.x * 4 + (threadIdx.x >> 6);
  int c = threadIdx.x & 63;
  if (node >= N_NODES) return;
  int off = S[node];
  int dg = deg[node];
  float s0 = 0.f, s1 = 0.f, s2 = 0.f, s3 = 0.f;
  int e = 0;
  for (; e + 4 <= dg; e += 4) {
    int a0 = slots[off + e];
    int a1 = slots[off + e + 1];
    int a2 = slots[off + e + 2];
    int a3 = slots[off + e + 3];
    s0 += h[a0 * H + c];
    s1 += h[a1 * H + c];
    s2 += h[a2 * H + c];
    s3 += h[a3 * H + c];
  }
  for (; e < dg; ++e) s0 += h[slots[off + e] * H + c];
  hsum[node * H + c] = (s0 + s1) + (s2 + s3);
}

// ---------------- bucketed transform: out = hsum@WL[d] + bl[d] + h@WR[d] ----
__global__ __launch_bounds__(256) void transform_kernel(
    float* __restrict__ h, const float* __restrict__ hsum,
    const int* __restrict__ blist, const int* __restrict__ bcnt,
    const int* __restrict__ boff, const float* __restrict__ wl,
    const float* __restrict__ bl, const float* __restrict__ wr,
    int jb21, int do_relu) {
  int b = blockIdx.y;
  int cnt = bcnt[jb21 + b];
  int start = blockIdx.x * 64;
  if (start >= cnt) return;
  int nIn = min(64, cnt - start);
  const int* lst = blist + boff[jb21 + b] + start;

  int tid = threadIdx.x;
  int qw = tid >> 6, lane = tid & 63;
  __shared__ float hsL[64 * 65];
  __shared__ float hcL[64 * 65];
  __shared__ int nodeS[64];

  for (int r = qw * 16; r < qw * 16 + 16; ++r) {
    int node = (r < nIn) ? lst[r] : -1;
    if (lane == 0) nodeS[r] = node;
    float hv = 0.f, sv = 0.f;
    if (node >= 0) {
      hv = h[node * H + lane];
      if (b) sv = hsum[node * H + lane];
    }
    hcL[lane * 65 + r] = hv;
    hsL[lane * 65 + r] = sv;
  }
  __syncthreads();

  if (b) {
    int qs = __builtin_amdgcn_readfirstlane(qw);
    const float* __restrict__ WL = wl + ((size_t)b << 12) + (qs << 4);
    const float* __restrict__ WR = wr + ((size_t)b << 12) + (qs << 4);
    const float* __restrict__ BL = bl + (b << 6) + (qs << 4);
    float acc[16];
#pragma unroll
    for (int k = 0; k < 16; ++k) acc[k] = BL[k];
#pragma unroll 4
    for (int f = 0; f < 64; ++f) {
      float hsf = hsL[f * 65 + lane];
      float hcf = hcL[f * 65 + lane];
#pragma unroll
      for (int k = 0; k < 16; ++k) acc[k] = fmaf(hsf, WL[f * H + k], acc[k]);
#pragma unroll
      for (int k = 0; k < 16; ++k) acc[k] = fmaf(hcf, WR[f * H + k], acc[k]);
    }
    if (do_relu) {
#pragma unroll
      for (int k = 0; k < 16; ++k) acc[k] = fmaxf(acc[k], 0.f);
    }
    __syncthreads();
#pragma unroll
    for (int k = 0; k < 16; ++k) hsL[(qw * 16 + k) * 65 + lane] = acc[k];
    __syncthreads();
    for (int r = qw * 16; r < qw * 16 + 16; ++r) {
      if (r < nIn) h[nodeS[r] * H + lane] = hsL[lane * 65 + r];
    }
  } else {
    for (int r = qw * 16; r < qw * 16 + 16; ++r) {
      if (r < nIn) {
        float v = hcL[lane * 65 + r];
        if (do_relu) v = fmaxf(v, 0.f);
        h[nodeS[r] * H + lane] = v;
      }
    }
  }
}

// ---------------- layernorm + residual ----------------
__global__ __launch_bounds__(256) void ln_kernel(
    float* __restrict__ h, const float* __restrict__ h0,
    const float* __restrict__ g, const float* __restrict__ b) {
  int node = blockIdx.x * 4 + (threadIdx.x >> 6);
  int c = threadIdx.x & 63;
  if (node >= N_NODES) return;
  int idx = node * H + c;
  float v = h[idx];
  float s = v;
#pragma unroll
  for (int off = 32; off > 0; off >>= 1) s += __shfl_xor(s, off, 64);
  float mu = s * (1.0f / H);
  float dv = v - mu;
  float q = dv * dv;
#pragma unroll
  for (int off = 32; off > 0; off >>= 1) q += __shfl_xor(q, off, 64);
  float inv = rsqrtf(q * (1.0f / H) + LN_EPS);
  h[idx] = dv * inv * g[c] + b[c] + h0[idx];
}

// ---------------- pool: LDS-aggregated (avoid 390-way same-address atomics) --
__global__ __launch_bounds__(256) void pool_kernel(
    const float* __restrict__ h, const int* __restrict__ batch,
    float* __restrict__ pooled) {
  __shared__ float sm[NUM_GRAPHS * H];  // 32 KB
  int t = threadIdx.x;
  for (int i = t; i < NUM_GRAPHS * H; i += 256) sm[i] = 0.f;
  __syncthreads();
  int lane = t & 63, w = t >> 6;
  const int per = (G_NODES + POOL_BLOCKS - 1) / POOL_BLOCKS;
  int start = blockIdx.x * per;
  int end = min(start + per, G_NODES);
  for (int node = start + w; node < end; node += 4) {
    int g = batch[node];
    atomicAdd(&sm[g * H + lane], h[node * H + lane]);
  }
  __syncthreads();
  for (int i = t; i < NUM_GRAPHS * H; i += 256) {
    float v = sm[i];
    if (v != 0.f) atomicAdd(&pooled[i], v);
  }
}

__global__ __launch_bounds__(64) void out_kernel(
    const float* __restrict__ pooled, const float* __restrict__ w,
    const float* __restrict__ b, float* __restrict__ out) {
  int gph = blockIdx.x;
  int c = threadIdx.x;
  float v = pooled[gph * H + c] * w[c];
#pragma unroll
  for (int off = 32; off > 0; off >>= 1) v += __shfl_xor(v, off, 64);
  if (c == 0) out[gph] = v + b[0];
}

extern "C" void kernel_launch(void* const* d_in, const int* in_sizes, int n_in,
                              void* d_out, int out_size, void* d_ws, size_t ws_size,
                              hipStream_t stream) {
  const float* x       = (const float*)d_in[0];
  const int*   ei_edge = (const int*)d_in[1];
  const int*   ei_sub  = (const int*)d_in[2];
  const int*   ei_ns   = (const int*)d_in[3];
  const int*   ei_sn   = (const int*)d_in[4];
  const int*   batch   = (const int*)d_in[7];
  const float* emb_w   = (const float*)d_in[8];
  const float* emb_b   = (const float*)d_in[9];
  const float* conv_wl = (const float*)d_in[10];
  const float* conv_bl = (const float*)d_in[11];
  const float* conv_wr = (const float*)d_in[12];
  const float* ln_g    = (const float*)d_in[13];
  const float* ln_b    = (const float*)d_in[14];
  const float* out_w   = (const float*)d_in[15];
  const float* out_b   = (const float*)d_in[16];
  float* out = (float*)d_out;

  const size_t HB = (size_t)N_NODES * H * sizeof(float);  // 25.6 MB
  char* ws = (char*)d_ws;
  float* h      = (float*)(ws);
  float* h0     = (float*)(ws + HB);
  float* hsum   = (float*)(ws + 2 * HB);
  int*   cursor = (int*)(ws + 2 * HB);                 // overlay (dead pre-gather)
  int*   bsum   = (int*)(ws + 2 * HB + 1600000);
  int*   deg4   = (int*)(ws + 3 * HB);                 // 1.6 MB
  int*   S      = (int*)(ws + 78400000);               // 1.6 MB
  int*   slots  = (int*)(ws + 80000000);               // 12.8 MB
  int*   bcnt   = (int*)(ws + 92800000);
  int*   boff   = (int*)(ws + 92800512);
  int*   bcur   = (int*)(ws + 92801024);
  int*   blist  = (int*)(ws + 92801536);               // 1.6 MB
  float* pooled = (float*)(ws + 94401536);             // 32 KB

  const int* e0 = ei_edge, *e1 = ei_ns, *e2 = ei_sub, *e3 = ei_sn;
  const int M = 4 * N_NODES;
  const int NB1 = (M + 1023) / 1024;  // 391

  hipMemsetAsync(deg4, 0, (size_t)M * sizeof(int), stream);
  hipMemsetAsync(bcnt, 0, 512, stream);

  emb_kernel<<<(N_NODES + 3) / 4, 256, 0, stream>>>(x, emb_w, emb_b, h, h0);

  count_kernel<<<dim3((N_EDGES + 255) / 256, 4), 256, 0, stream>>>(e0, e1, e2, e3, deg4);
  scan1<<<NB1, 256, 0, stream>>>(deg4, S, bsum, M);
  scan2<<<1, 512, 0, stream>>>(bsum, NB1);
  scan3<<<(M + 255) / 256, 256, 0, stream>>>(S, bsum, cursor, M);
  fill_kernel<<<dim3((N_EDGES + 255) / 256, 4), 256, 0, stream>>>(e0, e1, e2, e3, cursor, slots);

  bucket_count<<<dim3((N_NODES + 255) / 256, 4), 256, 0, stream>>>(deg4, bcnt);
  bucket_scan<<<1, 128, 0, stream>>>(bcnt, boff, bcur);
  bucket_fill<<<dim3((N_NODES + 255) / 256, 4), 256, 0, stream>>>(deg4, bcur, blist);

  const int TNB = (N_NODES + 63) / 64;  // 1563
  for (int j = 0; j < 4; ++j) {
    gather_kernel<<<(N_NODES + 3) / 4, 256, 0, stream>>>(
        S + j * N_NODES, deg4 + j * N_NODES, slots, h, hsum);
    transform_kernel<<<dim3(TNB, 21), 256, 0, stream>>>(
        h, hsum, blist, bcnt, boff,
        conv_wl + (size_t)j * 21 * H * H,
        conv_bl + (size_t)j * 21 * H,
        conv_wr + (size_t)j * 21 * H * H,
        j * 21, j < 3 ? 1 : 0);
  }

  ln_kernel<<<(N_NODES + 3) / 4, 256, 0, stream>>>(h, h0, ln_g, ln_b);

  hipMemsetAsync(pooled, 0, NUM_GRAPHS * H * sizeof(float), stream);
  pool_kernel<<<POOL_BLOCKS, 256, 0, stream>>>(h, batch, pooled);
  out_kernel<<<NUM_GRAPHS, 64, 0, stream>>>(pooled, out_w, out_b, out);
}

// Round 5
// 744.702 us; speedup vs baseline: 1.4861x; 1.4861x over previous
//
#include <hip/hip_runtime.h>

#define N_NODES 100000
#define G_NODES 50000
#define N_EDGES 800000
#define H 64
#define F_IN 32
#define MAX_DEG 20
#define NUM_GRAPHS 128
#define LN_EPS 1e-5f
#define POOL_BLOCKS 64

// Binned CSR build parameters: 512 bins over the 4*N key space.
#define NBINS 512
#define BPB 782            // keys per bin: 782*512 = 400384 >= 400000
#define CHUNK 6250         // edges per build block: 6250*512 = 3.2M
#define MKEYS (4 * N_NODES)
#define MEDGES (4 * N_EDGES)

// ---------------- embedding: h = x @ emb_w + emb_b (wave-per-node, lane=c) ----
__global__ __launch_bounds__(256) void emb_kernel(
    const float* __restrict__ x, const float* __restrict__ w,
    const float* __restrict__ b, float* __restrict__ h, float* __restrict__ h0) {
  int node = blockIdx.x * 4 + (threadIdx.x >> 6);
  int c = threadIdx.x & 63;
  if (node >= N_NODES) return;
  float xv = (c < F_IN) ? x[node * F_IN + c] : 0.0f;
  float acc = b[c];
#pragma unroll
  for (int f = 0; f < F_IN; ++f) {
    float xf = __shfl(xv, f, 64);
    acc = fmaf(xf, w[f * H + c], acc);
  }
  int idx = node * H + c;
  h[idx] = acc;
  h0[idx] = acc;
}

// ---------------- binned CSR build (no scattered global atomics) ------------
// R4 lesson: per-lane scattered device atomics write through at ~64B/line
// (fill/count ~500us combined). All per-edge atomics below are LDS-only.

// P1: per-block 512-bin LDS histogram of its 6250-edge chunk.
__global__ __launch_bounds__(256) void p1_bincount(
    const int* __restrict__ e0, const int* __restrict__ e1,
    const int* __restrict__ e2, const int* __restrict__ e3,
    int* __restrict__ cntT) {
  __shared__ int hist[NBINS];
  int t = threadIdx.x, b = blockIdx.x;
  for (int i = t; i < NBINS; i += 256) hist[i] = 0;
  __syncthreads();
  int j = b >> 7;  // 128 blocks per edge set
  const int* ei = (j == 0) ? e0 : (j == 1) ? e1 : (j == 2) ? e2 : e3;
  int ebase = (b & 127) * CHUNK;
  for (int i = t; i < CHUNK; i += 256) {
    int dst = ei[N_EDGES + ebase + i];
    int key = j * N_NODES + dst;
    atomicAdd(&hist[key / BPB], 1);
  }
  __syncthreads();
  for (int i = t; i < NBINS; i += 256) cntT[i * NBINS + b] = hist[i];
}

// P3: scatter (key,src) into per-(bin,block) reserved ranges; LDS cursors.
__global__ __launch_bounds__(256) void p3_binscatter(
    const int* __restrict__ e0, const int* __restrict__ e1,
    const int* __restrict__ e2, const int* __restrict__ e3,
    const int* __restrict__ offT, unsigned long long* __restrict__ binned) {
  __shared__ int cur[NBINS];
  int t = threadIdx.x, b = blockIdx.x;
  for (int i = t; i < NBINS; i += 256) cur[i] = offT[i * NBINS + b];
  __syncthreads();
  int j = b >> 7;
  const int* ei = (j == 0) ? e0 : (j == 1) ? e1 : (j == 2) ? e2 : e3;
  int ebase = (b & 127) * CHUNK;
  for (int i = t; i < CHUNK; i += 256) {
    int src = ei[ebase + i];
    int dst = ei[N_EDGES + ebase + i];
    int key = j * N_NODES + dst;
    int pos = atomicAdd(&cur[key / BPB], 1);
    binned[pos] = ((unsigned long long)(unsigned)key << 32) | (unsigned)src;
  }
}

// P4: one block per bin -> LDS degree histogram -> coalesced deg4 write.
__global__ __launch_bounds__(256) void p4_deg(
    const unsigned long long* __restrict__ binned, const int* __restrict__ offT,
    int* __restrict__ deg4) {
  __shared__ int hist[BPB];
  int t = threadIdx.x, bin = blockIdx.x;
  for (int i = t; i < BPB; i += 256) hist[i] = 0;
  __syncthreads();
  int start = offT[bin * NBINS];
  int end = (bin == NBINS - 1) ? MEDGES : offT[(bin + 1) * NBINS];
  int kb = bin * BPB;
  for (int i = start + t; i < end; i += 256) {
    int key = (int)(binned[i] >> 32);
    atomicAdd(&hist[key - kb], 1);
  }
  __syncthreads();
  for (int i = t; i < BPB; i += 256)
    if (kb + i < MKEYS) deg4[kb + i] = hist[i];
}

// P6: one block per bin -> LDS cursors from S -> slots written into the bin's
// ~25KB contiguous window (L2-resident, lines fully filled).
__global__ __launch_bounds__(256) void p6_slots(
    const unsigned long long* __restrict__ binned, const int* __restrict__ offT,
    const int* __restrict__ S, int* __restrict__ slots) {
  __shared__ int cur[BPB];
  int t = threadIdx.x, bin = blockIdx.x;
  int kb = bin * BPB;
  for (int i = t; i < BPB; i += 256) cur[i] = (kb + i < MKEYS) ? S[kb + i] : 0;
  __syncthreads();
  int start = offT[bin * NBINS];
  int end = (bin == NBINS - 1) ? MEDGES : offT[(bin + 1) * NBINS];
  for (int i = start + t; i < end; i += 256) {
    unsigned long long v = binned[i];
    int key = (int)(v >> 32);
    int pos = atomicAdd(&cur[key - kb], 1);
    slots[pos] = (int)(v & 0xffffffffULL);
  }
}

// ---------------- hierarchical exclusive scan (1024 elems/block) ------------
__global__ __launch_bounds__(256) void scan1(
    const int* __restrict__ in, int* __restrict__ S, int* __restrict__ bsum, int M) {
  int t = threadIdx.x;
  int base = blockIdx.x * 1024 + t * 4;
  int v0 = 0, v1 = 0, v2 = 0, v3 = 0;
  if (base + 3 < M) {
    int4 q = *(const int4*)(in + base);
    v0 = q.x; v1 = q.y; v2 = q.z; v3 = q.w;
  } else {
    if (base     < M) v0 = in[base];
    if (base + 1 < M) v1 = in[base + 1];
    if (base + 2 < M) v2 = in[base + 2];
    if (base + 3 < M) v3 = in[base + 3];
  }
  int s = v0 + v1 + v2 + v3;
  int incl = s;
#pragma unroll
  for (int off = 1; off < 64; off <<= 1) {
    int y = __shfl_up(incl, off, 64);
    if ((t & 63) >= off) incl += y;
  }
  __shared__ int wtot[4];
  if ((t & 63) == 63) wtot[t >> 6] = incl;
  __syncthreads();
  int wbase = 0;
  for (int w = 0; w < (t >> 6); ++w) wbase += wtot[w];
  int ex = wbase + incl - s;
  if (base < M) {
    int eo0 = ex, eo1 = ex + v0, eo2 = ex + v0 + v1, eo3 = ex + v0 + v1 + v2;
    if (base + 3 < M) {
      *(int4*)(S + base) = make_int4(eo0, eo1, eo2, eo3);
    } else {
      S[base] = eo0;
      if (base + 1 < M) S[base + 1] = eo1;
      if (base + 2 < M) S[base + 2] = eo2;
    }
  }
  if (t == 255) bsum[blockIdx.x] = wbase + incl;
}

__global__ __launch_bounds__(512) void scan2(int* __restrict__ bsum, int nb) {
  int t = threadIdx.x;
  int v = (t < nb) ? bsum[t] : 0;
  int incl = v;
#pragma unroll
  for (int off = 1; off < 64; off <<= 1) {
    int y = __shfl_up(incl, off, 64);
    if ((t & 63) >= off) incl += y;
  }
  __shared__ int wtot[8];
  if ((t & 63) == 63) wtot[t >> 6] = incl;
  __syncthreads();
  int wbase = 0;
  for (int w = 0; w < (t >> 6); ++w) wbase += wtot[w];
  if (t < nb) bsum[t] = wbase + incl - v;
}

__global__ __launch_bounds__(256) void scan3(
    int* __restrict__ S, const int* __restrict__ bsum, int M) {
  int i = blockIdx.x * 256 + threadIdx.x;
  if (i >= M) return;
  S[i] = S[i] + bsum[i >> 10];
}

// ---------------- degree-bucket lists (LDS-aggregated) ----------------------
__global__ __launch_bounds__(256) void bucket_count(
    const int* __restrict__ deg4, int* __restrict__ bcnt) {
  __shared__ int hist[21];
  int t = threadIdx.x;
  if (t < 21) hist[t] = 0;
  __syncthreads();
  int node = blockIdx.x * 256 + t;
  int j = blockIdx.y;
  if (node < N_NODES) {
    int d = deg4[j * N_NODES + node];
    int b = d < MAX_DEG ? d : MAX_DEG;
    atomicAdd(&hist[b], 1);
  }
  __syncthreads();
  if (t < 21 && hist[t]) atomicAdd(&bcnt[j * 21 + t], hist[t]);
}

__global__ __launch_bounds__(128) void bucket_scan(
    const int* __restrict__ bcnt, int* __restrict__ boff, int* __restrict__ bcur) {
  int t = threadIdx.x;
  int v = (t < 84) ? bcnt[t] : 0;
  int incl = v;
#pragma unroll
  for (int off = 1; off < 64; off <<= 1) {
    int y = __shfl_up(incl, off, 64);
    if ((t & 63) >= off) incl += y;
  }
  __shared__ int wt[2];
  if ((t & 63) == 63) wt[t >> 6] = incl;
  __syncthreads();
  int wbase = (t >> 6) ? wt[0] : 0;
  if (t < 84) {
    int ex = wbase + incl - v;
    boff[t] = ex;
    bcur[t] = ex;
  }
}

__global__ __launch_bounds__(256) void bucket_fill(
    const int* __restrict__ deg4, int* __restrict__ bcur, int* __restrict__ blist) {
  __shared__ int hist[21];
  __shared__ int base[21];
  int t = threadIdx.x;
  if (t < 21) hist[t] = 0;
  __syncthreads();
  int node = blockIdx.x * 256 + t;
  int j = blockIdx.y;
  int b = 0, lpos = 0;
  bool valid = (node < N_NODES);
  if (valid) {
    int d = deg4[j * N_NODES + node];
    b = d < MAX_DEG ? d : MAX_DEG;
    lpos = atomicAdd(&hist[b], 1);
  }
  __syncthreads();
  if (t < 21 && hist[t]) base[t] = atomicAdd(&bcur[j * 21 + t], hist[t]);
  __syncthreads();
  if (valid) blist[base[b] + lpos] = node;
}

// ---------------- gather: hsum[i] = sum_{j->i} h[j] (CSR, no atomics) -------
__global__ __launch_bounds__(256) void gather_kernel(
    const int* __restrict__ S, const int* __restrict__ deg,
    const int* __restrict__ slots, const float* __restrict__ h,
    float* __restrict__ hsum) {
  int node = blockIdx.x * 4 + (threadIdx.x >> 6);
  int c = threadIdx.x & 63;
  if (node >= N_NODES) return;
  int off = S[node];
  int dg = deg[node];
  float s0 = 0.f, s1 = 0.f, s2 = 0.f, s3 = 0.f;
  int e = 0;
  for (; e + 4 <= dg; e += 4) {
    int a0 = slots[off + e];
    int a1 = slots[off + e + 1];
    int a2 = slots[off + e + 2];
    int a3 = slots[off + e + 3];
    s0 += h[a0 * H + c];
    s1 += h[a1 * H + c];
    s2 += h[a2 * H + c];
    s3 += h[a3 * H + c];
  }
  for (; e < dg; ++e) s0 += h[slots[off + e] * H + c];
  hsum[node * H + c] = (s0 + s1) + (s2 + s3);
}

// ---------------- bucketed transform: out = hsum@WL[d] + bl[d] + h@WR[d] ----
__global__ __launch_bounds__(256) void transform_kernel(
    float* __restrict__ h, const float* __restrict__ hsum,
    const int* __restrict__ blist, const int* __restrict__ bcnt,
    const int* __restrict__ boff, const float* __restrict__ wl,
    const float* __restrict__ bl, const float* __restrict__ wr,
    int jb21, int do_relu) {
  int b = blockIdx.y;
  int cnt = bcnt[jb21 + b];
  int start = blockIdx.x * 64;
  if (start >= cnt) return;
  int nIn = min(64, cnt - start);
  const int* lst = blist + boff[jb21 + b] + start;

  int tid = threadIdx.x;
  int qw = tid >> 6, lane = tid & 63;
  __shared__ float hsL[64 * 65];
  __shared__ float hcL[64 * 65];
  __shared__ int nodeS[64];

  for (int r = qw * 16; r < qw * 16 + 16; ++r) {
    int node = (r < nIn) ? lst[r] : -1;
    if (lane == 0) nodeS[r] = node;
    float hv = 0.f, sv = 0.f;
    if (node >= 0) {
      hv = h[node * H + lane];
      if (b) sv = hsum[node * H + lane];
    }
    hcL[lane * 65 + r] = hv;
    hsL[lane * 65 + r] = sv;
  }
  __syncthreads();

  if (b) {
    int qs = __builtin_amdgcn_readfirstlane(qw);
    const float* __restrict__ WL = wl + ((size_t)b << 12) + (qs << 4);
    const float* __restrict__ WR = wr + ((size_t)b << 12) + (qs << 4);
    const float* __restrict__ BL = bl + (b << 6) + (qs << 4);
    float acc[16];
#pragma unroll
    for (int k = 0; k < 16; ++k) acc[k] = BL[k];
#pragma unroll 4
    for (int f = 0; f < 64; ++f) {
      float hsf = hsL[f * 65 + lane];
      float hcf = hcL[f * 65 + lane];
#pragma unroll
      for (int k = 0; k < 16; ++k) acc[k] = fmaf(hsf, WL[f * H + k], acc[k]);
#pragma unroll
      for (int k = 0; k < 16; ++k) acc[k] = fmaf(hcf, WR[f * H + k], acc[k]);
    }
    if (do_relu) {
#pragma unroll
      for (int k = 0; k < 16; ++k) acc[k] = fmaxf(acc[k], 0.f);
    }
    __syncthreads();
#pragma unroll
    for (int k = 0; k < 16; ++k) hsL[(qw * 16 + k) * 65 + lane] = acc[k];
    __syncthreads();
    for (int r = qw * 16; r < qw * 16 + 16; ++r) {
      if (r < nIn) h[nodeS[r] * H + lane] = hsL[lane * 65 + r];
    }
  } else {
    for (int r = qw * 16; r < qw * 16 + 16; ++r) {
      if (r < nIn) {
        float v = hcL[lane * 65 + r];
        if (do_relu) v = fmaxf(v, 0.f);
        h[nodeS[r] * H + lane] = v;
      }
    }
  }
}

// ---------------- layernorm + residual ----------------
__global__ __launch_bounds__(256) void ln_kernel(
    float* __restrict__ h, const float* __restrict__ h0,
    const float* __restrict__ g, const float* __restrict__ b) {
  int node = blockIdx.x * 4 + (threadIdx.x >> 6);
  int c = threadIdx.x & 63;
  if (node >= N_NODES) return;
  int idx = node * H + c;
  float v = h[idx];
  float s = v;
#pragma unroll
  for (int off = 32; off > 0; off >>= 1) s += __shfl_xor(s, off, 64);
  float mu = s * (1.0f / H);
  float dv = v - mu;
  float q = dv * dv;
#pragma unroll
  for (int off = 32; off > 0; off >>= 1) q += __shfl_xor(q, off, 64);
  float inv = rsqrtf(q * (1.0f / H) + LN_EPS);
  h[idx] = dv * inv * g[c] + b[c] + h0[idx];
}

// ---------------- pool: LDS-aggregated ----------------
__global__ __launch_bounds__(256) void pool_kernel(
    const float* __restrict__ h, const int* __restrict__ batch,
    float* __restrict__ pooled) {
  __shared__ float sm[NUM_GRAPHS * H];  // 32 KB
  int t = threadIdx.x;
  for (int i = t; i < NUM_GRAPHS * H; i += 256) sm[i] = 0.f;
  __syncthreads();
  int lane = t & 63, w = t >> 6;
  const int per = (G_NODES + POOL_BLOCKS - 1) / POOL_BLOCKS;
  int start = blockIdx.x * per;
  int end = min(start + per, G_NODES);
  for (int node = start + w; node < end; node += 4) {
    int g = batch[node];
    atomicAdd(&sm[g * H + lane], h[node * H + lane]);
  }
  __syncthreads();
  for (int i = t; i < NUM_GRAPHS * H; i += 256) {
    float v = sm[i];
    if (v != 0.f) atomicAdd(&pooled[i], v);
  }
}

__global__ __launch_bounds__(64) void out_kernel(
    const float* __restrict__ pooled, const float* __restrict__ w,
    const float* __restrict__ b, float* __restrict__ out) {
  int gph = blockIdx.x;
  int c = threadIdx.x;
  float v = pooled[gph * H + c] * w[c];
#pragma unroll
  for (int off = 32; off > 0; off >>= 1) v += __shfl_xor(v, off, 64);
  if (c == 0) out[gph] = v + b[0];
}

extern "C" void kernel_launch(void* const* d_in, const int* in_sizes, int n_in,
                              void* d_out, int out_size, void* d_ws, size_t ws_size,
                              hipStream_t stream) {
  const float* x       = (const float*)d_in[0];
  const int*   ei_edge = (const int*)d_in[1];
  const int*   ei_sub  = (const int*)d_in[2];
  const int*   ei_ns   = (const int*)d_in[3];
  const int*   ei_sn   = (const int*)d_in[4];
  const int*   batch   = (const int*)d_in[7];
  const float* emb_w   = (const float*)d_in[8];
  const float* emb_b   = (const float*)d_in[9];
  const float* conv_wl = (const float*)d_in[10];
  const float* conv_bl = (const float*)d_in[11];
  const float* conv_wr = (const float*)d_in[12];
  const float* ln_g    = (const float*)d_in[13];
  const float* ln_b    = (const float*)d_in[14];
  const float* out_w   = (const float*)d_in[15];
  const float* out_b   = (const float*)d_in[16];
  float* out = (float*)d_out;

  const size_t HB = (size_t)N_NODES * H * sizeof(float);  // 25.6 MB
  char* ws = (char*)d_ws;
  float* h      = (float*)(ws);
  float* h0     = (float*)(ws + HB);
  float* hsum   = (float*)(ws + 2 * HB);
  // Build-phase overlays (all dead once emb_kernel runs):
  unsigned long long* binned = (unsigned long long*)(ws);       // 25.6 MB on h
  int*   cntT   = (int*)(ws + HB);                              // 1 MB on h0
  int*   offT   = (int*)(ws + HB + 0x100000);                   // 1 MB
  int*   bsumA  = (int*)(ws + HB + 0x300000);                   // 2 KB
  // Persistent:
  int*   deg4   = (int*)(ws + 3 * HB);                          // 1.6 MB
  int*   S      = (int*)(ws + 78400000);                        // 1.6 MB
  int*   slots  = (int*)(ws + 80000000);                        // 12.8 MB
  int*   bcnt   = (int*)(ws + 92800000);
  int*   boff   = (int*)(ws + 92800512);
  int*   bcur   = (int*)(ws + 92801024);
  int*   blist  = (int*)(ws + 92801536);                        // 1.6 MB
  float* pooled = (float*)(ws + 94401536);                      // 32 KB

  const int* e0 = ei_edge, *e1 = ei_ns, *e2 = ei_sub, *e3 = ei_sn;
  const int MC = NBINS * NBINS;        // 262144 cntT entries
  const int NB_MC = MC / 1024;         // 256
  const int NB_MK = (MKEYS + 1023) / 1024;  // 391

  hipMemsetAsync(bcnt, 0, 512, stream);

  // --- binned CSR build ---
  p1_bincount<<<NBINS, 256, 0, stream>>>(e0, e1, e2, e3, cntT);
  scan1<<<NB_MC, 256, 0, stream>>>(cntT, offT, bsumA, MC);
  scan2<<<1, 512, 0, stream>>>(bsumA, NB_MC);
  scan3<<<MC / 256, 256, 0, stream>>>(offT, bsumA, MC);
  p3_binscatter<<<NBINS, 256, 0, stream>>>(e0, e1, e2, e3, offT, binned);
  p4_deg<<<NBINS, 256, 0, stream>>>(binned, offT, deg4);
  scan1<<<NB_MK, 256, 0, stream>>>(deg4, S, bsumA, MKEYS);
  scan2<<<1, 512, 0, stream>>>(bsumA, NB_MK);
  scan3<<<(MKEYS + 255) / 256, 256, 0, stream>>>(S, bsumA, MKEYS);
  p6_slots<<<NBINS, 256, 0, stream>>>(binned, offT, S, slots);

  bucket_count<<<dim3((N_NODES + 255) / 256, 4), 256, 0, stream>>>(deg4, bcnt);
  bucket_scan<<<1, 128, 0, stream>>>(bcnt, boff, bcur);
  bucket_fill<<<dim3((N_NODES + 255) / 256, 4), 256, 0, stream>>>(deg4, bcur, blist);

  // --- network ---
  emb_kernel<<<(N_NODES + 3) / 4, 256, 0, stream>>>(x, emb_w, emb_b, h, h0);

  const int TNB = (N_NODES + 63) / 64;  // 1563
  for (int j = 0; j < 4; ++j) {
    gather_kernel<<<(N_NODES + 3) / 4, 256, 0, stream>>>(
        S + j * N_NODES, deg4 + j * N_NODES, slots, h, hsum);
    transform_kernel<<<dim3(TNB, 21), 256, 0, stream>>>(
        h, hsum, blist, bcnt, boff,
        conv_wl + (size_t)j * 21 * H * H,
        conv_bl + (size_t)j * 21 * H,
        conv_wr + (size_t)j * 21 * H * H,
        j * 21, j < 3 ? 1 : 0);
  }

  ln_kernel<<<(N_NODES + 3) / 4, 256, 0, stream>>>(h, h0, ln_g, ln_b);

  hipMemsetAsync(pooled, 0, NUM_GRAPHS * H * sizeof(float), stream);
  pool_kernel<<<POOL_BLOCKS, 256, 0, stream>>>(h, batch, pooled);
  out_kernel<<<NUM_GRAPHS, 64, 0, stream>>>(pooled, out_w, out_b, out);
}